// Round 1
// baseline (358.744 us; speedup 1.0000x reference)
//
#include <hip/hip_runtime.h>

#define EE 256
#define SS 2048
#define BB 64
#define RN 50
#define OSTR 8242   // 50 + 4*2048

typedef __attribute__((ext_vector_type(4))) float vf4;
typedef __attribute__((ext_vector_type(8))) short s8v;
typedef __attribute__((ext_vector_type(4))) unsigned short u16x4;

__device__ __forceinline__ unsigned short f2bf(float f){
  unsigned int u = __float_as_uint(f);
  u += 0x7fffu + ((u >> 16) & 1u);   // RNE
  return (unsigned short)(u >> 16);
}
__device__ __forceinline__ float sigm(float x){ return 1.0f/(1.0f + __expf(-x)); }
__device__ __forceinline__ float dot4(vf4 a, vf4 b){ return a.x*b.x + a.y*b.y + a.z*b.z + a.w*b.w; }

// ---------------- 1) LSTM chain: h1,h2,h3 (per-b independent) ----------------
__global__ __launch_bounds__(256) void k_lstm(
  const float* __restrict__ enc, const float* __restrict__ h0, const float* __restrict__ c0,
  const int* __restrict__ r_in, const int* __restrict__ k1, const int* __restrict__ k2,
  const float* __restrict__ W_ih, const float* __restrict__ W_hh,
  const float* __restrict__ b_ih, const float* __restrict__ b_hh,
  const float* __restrict__ sos, const float* __restrict__ rel,
  float* __restrict__ hs)
{
  int b = blockIdx.x, t = threadIdx.x;
  __shared__ float xs[3][EE], hsh[EE];
  xs[0][t] = sos[t];
  xs[1][t] = rel[r_in[b]*EE + t];
  int i1 = k1[b], i2 = k2[b];
  xs[2][t] = enc[((size_t)b*SS + i1)*EE + t] + enc[((size_t)b*SS + i2)*EE + t];
  hsh[t] = h0[b*EE + t];
  float cv = c0[b*EE + t];
  float bs0 = b_ih[t]        + b_hh[t];
  float bs1 = b_ih[EE+t]     + b_hh[EE+t];
  float bs2 = b_ih[2*EE+t]   + b_hh[2*EE+t];
  float bs3 = b_ih[3*EE+t]   + b_hh[3*EE+t];
  const vf4* wi0 = (const vf4*)(W_ih + (size_t)(0*EE+t)*EE);
  const vf4* wi1 = (const vf4*)(W_ih + (size_t)(1*EE+t)*EE);
  const vf4* wi2 = (const vf4*)(W_ih + (size_t)(2*EE+t)*EE);
  const vf4* wi3 = (const vf4*)(W_ih + (size_t)(3*EE+t)*EE);
  const vf4* wh0 = (const vf4*)(W_hh + (size_t)(0*EE+t)*EE);
  const vf4* wh1 = (const vf4*)(W_hh + (size_t)(1*EE+t)*EE);
  const vf4* wh2 = (const vf4*)(W_hh + (size_t)(2*EE+t)*EE);
  const vf4* wh3 = (const vf4*)(W_hh + (size_t)(3*EE+t)*EE);
  __syncthreads();
  for (int st = 0; st < 3; ++st){
    float a0=bs0, a1=bs1, a2=bs2, a3=bs3;
    const vf4* xv = (const vf4*)xs[st];
    const vf4* hv = (const vf4*)hsh;
    #pragma unroll 4
    for (int k = 0; k < EE/4; ++k){
      vf4 x = xv[k], h = hv[k], w;
      w = wi0[k]; a0 += dot4(w,x);
      w = wi1[k]; a1 += dot4(w,x);
      w = wi2[k]; a2 += dot4(w,x);
      w = wi3[k]; a3 += dot4(w,x);
      w = wh0[k]; a0 += dot4(w,h);
      w = wh1[k]; a1 += dot4(w,h);
      w = wh2[k]; a2 += dot4(w,h);
      w = wh3[k]; a3 += dot4(w,h);
    }
    float ig = sigm(a0), fg = sigm(a1), gg = tanhf(a2), og = sigm(a3);
    cv = fg*cv + ig*gg;
    float hn = og * tanhf(cv);
    __syncthreads();
    hsh[t] = hn;
    hs[((size_t)st*BB + b)*EE + t] = hn;
    __syncthreads();
  }
}

// ---------------- 2) scores for all 3 queries + per-chunk softmax stats ------
__global__ __launch_bounds__(256) void k_scores(
  const float* __restrict__ enc, const float* __restrict__ hs,
  float* __restrict__ scw, float* __restrict__ stats)
{
  int bid = blockIdx.x; int b = bid >> 3, ch = bid & 7;
  int tid = threadIdx.x, lane = tid & 63, wv = tid >> 6;
  __shared__ float hsm[3][EE];
  __shared__ float red[3][4];
  __shared__ float mg[3];
  for (int i = tid; i < 3*EE; i += 256) hsm[i>>8][i&255] = hs[((size_t)(i>>8)*BB + b)*EE + (i&255)];
  __syncthreads();
  int s = ch*256 + tid;
  const vf4* er = (const vf4*)(enc + ((size_t)b*SS + s)*EE);
  const vf4* q0 = (const vf4*)hsm[0];
  const vf4* q1 = (const vf4*)hsm[1];
  const vf4* q2 = (const vf4*)hsm[2];
  float a0=0.f, a1=0.f, a2=0.f;
  #pragma unroll 8
  for (int k = 0; k < EE/4; ++k){
    vf4 ev = er[k];
    a0 += dot4(ev, q0[k]);
    a1 += dot4(ev, q1[k]);
    a2 += dot4(ev, q2[k]);
  }
  scw[(size_t)(0*BB+b)*SS + s] = a0;
  scw[(size_t)(1*BB+b)*SS + s] = a1;
  scw[(size_t)(2*BB+b)*SS + s] = a2;
  float m0=a0, m1=a1, m2=a2;
  #pragma unroll
  for (int d=1; d<64; d<<=1){
    m0 = fmaxf(m0, __shfl_xor(m0,d));
    m1 = fmaxf(m1, __shfl_xor(m1,d));
    m2 = fmaxf(m2, __shfl_xor(m2,d));
  }
  if (lane==0){ red[0][wv]=m0; red[1][wv]=m1; red[2][wv]=m2; }
  __syncthreads();
  if (tid < 3) mg[tid] = fmaxf(fmaxf(red[tid][0],red[tid][1]), fmaxf(red[tid][2],red[tid][3]));
  __syncthreads();
  float e0 = __expf(a0-mg[0]), e1 = __expf(a1-mg[1]), e2 = __expf(a2-mg[2]);
  #pragma unroll
  for (int d=1; d<64; d<<=1){
    e0 += __shfl_xor(e0,d); e1 += __shfl_xor(e1,d); e2 += __shfl_xor(e2,d);
  }
  if (lane==0){ red[0][wv]=e0; red[1][wv]=e1; red[2][wv]=e2; }
  __syncthreads();
  if (tid < 3){
    float l = red[tid][0]+red[tid][1]+red[tid][2]+red[tid][3];
    int o = ((tid*BB + b)*8 + ch)*2;
    stats[o] = mg[tid]; stats[o+1] = l;
  }
}

// ---------------- 3) mix (weighted sum) -- writes over scw region (aliased) --
__global__ __launch_bounds__(256) void k_mix(
  const float* __restrict__ enc, const float* __restrict__ scm,
  const float* __restrict__ stats, float* __restrict__ mixc)
{
  int bid = blockIdx.x; int b = bid >> 3, ch = bid & 7;
  int tid = threadIdx.x, lane = tid & 63, wv = tid >> 6;
  __shared__ float wgt[3][256];
  __shared__ vf4 mpart[4][3][64];
  float mm[3], inv[3];
  #pragma unroll
  for (int t=0;t<3;t++){
    float m = -1e30f;
    for (int c=0;c<8;c++) m = fmaxf(m, stats[((t*BB+b)*8 + c)*2]);
    float l = 0.f;
    for (int c=0;c<8;c++){ int o=((t*BB+b)*8+c)*2; l += stats[o+1]*__expf(stats[o]-m); }
    mm[t]=m; inv[t]=1.0f/l;
  }
  int s = ch*256 + tid;
  wgt[0][tid] = __expf(scm[(size_t)(0*BB+b)*SS + s] - mm[0]) * inv[0];
  wgt[1][tid] = __expf(scm[(size_t)(1*BB+b)*SS + s] - mm[1]) * inv[1];
  wgt[2][tid] = __expf(scm[(size_t)(2*BB+b)*SS + s] - mm[2]) * inv[2];
  __syncthreads();
  vf4 a0 = (vf4)0.0f, a1 = (vf4)0.0f, a2 = (vf4)0.0f;
  for (int i=0;i<64;++i){
    int sl = wv*64 + i;
    vf4 ev = *(const vf4*)(enc + ((size_t)b*SS + ch*256 + sl)*EE + lane*4);
    a0 += ev*wgt[0][sl]; a1 += ev*wgt[1][sl]; a2 += ev*wgt[2][sl];
  }
  mpart[wv][0][lane]=a0; mpart[wv][1][lane]=a1; mpart[wv][2][lane]=a2;
  __syncthreads();
  if (tid < 192){
    int t = tid >> 6, e4 = tid & 63;
    vf4 sum = mpart[0][t][e4] + mpart[1][t][e4] + mpart[2][t][e4] + mpart[3][t][e4];
    *(vf4*)(mixc + ((size_t)(t*BB+b)*8 + ch)*EE + e4*4) = sum;
  }
}

// ---------------- 4) out_t = tanh([mix,h]W_attn^T+b); t1 logits; V vectors ---
__global__ __launch_bounds__(256) void k_post(
  const float* __restrict__ mixc, const float* __restrict__ hs,
  const float* __restrict__ W_attn, const float* __restrict__ b_attn,
  const float* __restrict__ W_rel, const float* __restrict__ b_rel,
  const float* __restrict__ W_conv, const float* __restrict__ b_conv,
  float* __restrict__ out, float* __restrict__ vv)
{
  int b = blockIdx.x, t = threadIdx.x;
  __shared__ float comb[3][2*EE];
  __shared__ float o1[EE], o2[EE], o3[EE];
  #pragma unroll
  for (int q=0;q<3;q++){
    float m = 0.f;
    for (int c=0;c<8;c++) m += mixc[((size_t)(q*BB+b)*8 + c)*EE + t];
    comb[q][t] = m;
    comb[q][EE+t] = hs[((size_t)q*BB + b)*EE + t];
  }
  __syncthreads();
  float a0 = b_attn[t], a1 = a0, a2 = a0;
  const vf4* wr = (const vf4*)(W_attn + (size_t)t*2*EE);
  const vf4* c0v = (const vf4*)comb[0];
  const vf4* c1v = (const vf4*)comb[1];
  const vf4* c2v = (const vf4*)comb[2];
  #pragma unroll 4
  for (int k=0;k<2*EE/4;++k){
    vf4 w = wr[k];
    a0 += dot4(w, c0v[k]); a1 += dot4(w, c1v[k]); a2 += dot4(w, c2v[k]);
  }
  o1[t]=tanhf(a0); o2[t]=tanhf(a1); o3[t]=tanhf(a2);
  __syncthreads();
  if (t < RN){
    float acc = b_rel[t];
    const vf4* wrel = (const vf4*)(W_rel + (size_t)t*EE);
    const vf4* ov = (const vf4*)o1;
    for (int k=0;k<EE/4;++k) acc += dot4(wrel[k], ov[k]);
    out[(size_t)b*OSTR + t] = acc;
  }
  // vec-part of conv: V_k[o] = sum_i out[i]*W_conv[o, 256+i, k]
  float va0=0,va1=0,va2=0, vb0=0,vb1=0,vb2=0;
  const float* wc = W_conv + (size_t)t*2*EE*3 + EE*3;
  for (int i=0;i<EE;++i){
    float w0 = wc[i*3+0], w1 = wc[i*3+1], w2 = wc[i*3+2];
    float x2 = o2[i], x3 = o3[i];
    va0 += x2*w0; va1 += x2*w1; va2 += x2*w2;
    vb0 += x3*w0; vb1 += x3*w1; vb2 += x3*w2;
  }
  float bc = b_conv[t];
  vv[((0*3+0)*BB + b)*EE + t] = va0+va1+va2+bc;  // interior
  vv[((0*3+1)*BB + b)*EE + t] = va1+va2+bc;      // s==0 (tap0 clipped)
  vv[((0*3+2)*BB + b)*EE + t] = va0+va1+bc;      // s==S-1 (tap2 clipped)
  vv[((1*3+0)*BB + b)*EE + t] = vb0+vb1+vb2+bc;
  vv[((1*3+1)*BB + b)*EE + t] = vb1+vb2+bc;
  vv[((1*3+2)*BB + b)*EE + t] = vb0+vb1+bc;
}

// ---------------- 5) pack B (= W_conv enc-channels) into MFMA-frag order -----
__global__ __launch_bounds__(256) void k_bprep(const float* __restrict__ W_conv,
                                               unsigned short* __restrict__ Bp)
{
  int gid = blockIdx.x*256 + threadIdx.x;   // < 24576
  int kc  = gid >> 10;
  int rem = gid & 1023;
  int ni  = rem >> 6;
  int l   = rem & 63;
  int o   = ni*16 + (l & 15);
  int kbase = kc*32 + ((l >> 4) << 3);
  u16x4 lo4, hi4;
  #pragma unroll
  for (int j=0;j<8;++j){
    int k = kbase + j; int ktap = k >> 8; int i = k & 255;
    unsigned short v = f2bf(W_conv[((size_t)o*512 + i)*3 + ktap]);
    if (j<4){ if(j==0)lo4.x=v; else if(j==1)lo4.y=v; else if(j==2)lo4.z=v; else lo4.w=v; }
    else    { if(j==4)hi4.x=v; else if(j==5)hi4.y=v; else if(j==6)hi4.z=v; else hi4.w=v; }
  }
  u16x4* dst = (u16x4*)(Bp + (size_t)gid*8);
  dst[0] = lo4; dst[1] = hi4;
}

// ---------------- 6) conv GEMM (M=BS,N=256,K=768) + fused relu-dot epilogue --
__global__ __launch_bounds__(256) void k_conv(
  const float* __restrict__ enc, const unsigned short* __restrict__ Bp,
  const float* __restrict__ vv,
  const float* __restrict__ W_e1, const float* __restrict__ b_e1,
  const float* __restrict__ W_e2, const float* __restrict__ b_e2,
  float* __restrict__ out)
{
  int stile = blockIdx.x, b = blockIdx.y;
  int s0 = stile*64;
  int tid = threadIdx.x, lane = tid & 63, w = tid >> 6;
  int lo = lane & 15, hi = lane >> 4;
  __shared__ __align__(16) unsigned short Ab[66*256];  // rows s0-1 .. s0+64, bf16, swizzled
  __shared__ float part[4][64][4];

  {  // stage A (fp32 -> bf16) with XOR swizzle
    const float* eb = enc + (size_t)b*SS*EE;
    for (int idx = tid; idx < 66*64; idx += 256){
      int r = idx >> 6, c4 = idx & 63;
      int s = s0 - 1 + r;
      vf4 v = (vf4)0.0f;
      if (s >= 0 && s < SS) v = *(const vf4*)(eb + (size_t)s*EE + c4*4);
      u16x4 pk; pk.x=f2bf(v.x); pk.y=f2bf(v.y); pk.z=f2bf(v.z); pk.w=f2bf(v.w);
      int byte = (r*512 + c4*8) ^ ((r & 7) << 4);
      *(u16x4*)((char*)Ab + byte) = pk;
    }
  }
  __syncthreads();

  vf4 acc[4][4];
  #pragma unroll
  for (int mi=0;mi<4;++mi){
    #pragma unroll
    for (int ni=0;ni<4;++ni) acc[mi][ni] = (vf4)0.0f;
  }
  const s8v* Bp8 = (const s8v*)Bp;
  s8v bf[4], bfn[4];
  #pragma unroll
  for (int ni=0;ni<4;++ni) bf[ni] = Bp8[((0*16 + (w*4+ni)) << 6) + lane];

  for (int kc=0; kc<24; ++kc){
    int ktap = kc >> 3;
    int colb = ((kc & 7) << 6) + (hi << 4);
    s8v af[4];
    #pragma unroll
    for (int mi=0;mi<4;++mi){
      int row = mi*16 + lo + ktap;
      int byte = row*512 + (colb ^ ((row & 7) << 4));
      af[mi] = *(const s8v*)((const char*)Ab + byte);
    }
    if (kc < 23){
      #pragma unroll
      for (int ni=0;ni<4;++ni) bfn[ni] = Bp8[(((kc+1)*16 + (w*4+ni)) << 6) + lane];
    }
    #pragma unroll
    for (int mi=0;mi<4;++mi){
      #pragma unroll
      for (int ni=0;ni<4;++ni)
        acc[mi][ni] = __builtin_amdgcn_mfma_f32_16x16x32_bf16(af[mi], bf[ni], acc[mi][ni], 0, 0, 0);
    }
    #pragma unroll
    for (int ni=0;ni<4;++ni) bf[ni] = bfn[ni];
  }

  // fused epilogue: e = relu(conv_enc + V + b_conv) . w{1,2} for both streams
  float vaI[4],vaL[4],vaR[4],vbI[4],vbL[4],vbR[4],w1v[4],w2v[4];
  #pragma unroll
  for (int ni=0;ni<4;++ni){
    int o = w*64 + ni*16 + lo;
    vaI[ni] = vv[((0*3+0)*BB + b)*EE + o];
    vaL[ni] = vv[((0*3+1)*BB + b)*EE + o];
    vaR[ni] = vv[((0*3+2)*BB + b)*EE + o];
    vbI[ni] = vv[((1*3+0)*BB + b)*EE + o];
    vbL[ni] = vv[((1*3+1)*BB + b)*EE + o];
    vbR[ni] = vv[((1*3+2)*BB + b)*EE + o];
    w1v[ni] = W_e1[o]; w2v[ni] = W_e2[o];
  }
  float be1 = b_e1[0], be2 = b_e2[0];
  #pragma unroll
  for (int mi=0;mi<4;++mi){
    #pragma unroll
    for (int j=0;j<4;++j){
      int m = mi*16 + hi*4 + j;
      int s = s0 + m;
      float p0=0,p1=0,p2=0,p3=0;
      #pragma unroll
      for (int ni=0;ni<4;++ni){
        float cvv = acc[mi][ni][j];
        float va = vaI[ni], vb = vbI[ni];
        if (s == 0){ va = vaL[ni]; vb = vbL[ni]; }
        else if (s == SS-1){ va = vaR[ni]; vb = vbR[ni]; }
        float ca = fmaxf(cvv + va, 0.0f);
        float cb = fmaxf(cvv + vb, 0.0f);
        p0 += ca*w1v[ni]; p1 += ca*w2v[ni];
        p2 += cb*w1v[ni]; p3 += cb*w2v[ni];
      }
      #pragma unroll
      for (int d=1; d<16; d<<=1){
        p0 += __shfl_xor(p0,d); p1 += __shfl_xor(p1,d);
        p2 += __shfl_xor(p2,d); p3 += __shfl_xor(p3,d);
      }
      if (lo == 0){ part[w][m][0]=p0; part[w][m][1]=p1; part[w][m][2]=p2; part[w][m][3]=p3; }
    }
  }
  __syncthreads();
  {
    int m = tid >> 2, oi = tid & 3;
    float r = part[0][m][oi] + part[1][m][oi] + part[2][m][oi] + part[3][m][oi];
    r += (oi & 1) ? be2 : be1;
    out[(size_t)b*OSTR + RN + oi*SS + (s0 + m)] = r;
  }
}

extern "C" void kernel_launch(void* const* d_in, const int* in_sizes, int n_in,
                              void* d_out, int out_size, void* d_ws, size_t ws_size,
                              hipStream_t stream)
{
  const float* enc   = (const float*)d_in[0];
  const float* h0    = (const float*)d_in[1];
  const float* c0    = (const float*)d_in[2];
  const int*   r_in  = (const int*)d_in[3];
  const int*   k1    = (const int*)d_in[4];
  const int*   k2    = (const int*)d_in[5];
  const float* W_ih  = (const float*)d_in[6];
  const float* W_hh  = (const float*)d_in[7];
  const float* b_ih  = (const float*)d_in[8];
  const float* b_hh  = (const float*)d_in[9];
  const float* W_attn= (const float*)d_in[10];
  const float* b_attn= (const float*)d_in[11];
  const float* W_conv= (const float*)d_in[12];
  const float* b_conv= (const float*)d_in[13];
  const float* sos   = (const float*)d_in[14];
  const float* rel   = (const float*)d_in[15];
  const float* W_rel = (const float*)d_in[16];
  const float* b_rel = (const float*)d_in[17];
  const float* W_e1  = (const float*)d_in[18];
  const float* b_e1  = (const float*)d_in[19];
  const float* W_e2  = (const float*)d_in[20];
  const float* b_e2  = (const float*)d_in[21];
  float* out = (float*)d_out;
  char* ws = (char*)d_ws;

  float* hs    = (float*)(ws);                 // 3*64*256 f32        (196608 B)
  float* vv    = (float*)(ws + 196608);        // 2*3*64*256 f32      (393216 B)
  float* stats = (float*)(ws + 589824);        // 3*64*8*2 f32        ( 12288 B)
  float* scw   = (float*)(ws + 602112);        // 3*64*2048 f32       (1572864 B) [reused as mixc]
  unsigned short* Bp = (unsigned short*)(ws + 2174976); // 24*16*64*8 bf16 (393216 B)

  hipLaunchKernelGGL(k_lstm,  dim3(64),     dim3(256), 0, stream,
                     enc,h0,c0,r_in,k1,k2,W_ih,W_hh,b_ih,b_hh,sos,rel,hs);
  hipLaunchKernelGGL(k_scores,dim3(512),    dim3(256), 0, stream, enc, hs, scw, stats);
  hipLaunchKernelGGL(k_mix,   dim3(512),    dim3(256), 0, stream, enc, scw, stats, scw);
  hipLaunchKernelGGL(k_post,  dim3(64),     dim3(256), 0, stream,
                     scw, hs, W_attn,b_attn, W_rel,b_rel, W_conv,b_conv, out, vv);
  hipLaunchKernelGGL(k_bprep, dim3(96),     dim3(256), 0, stream, W_conv, Bp);
  hipLaunchKernelGGL(k_conv,  dim3(32,64),  dim3(256), 0, stream,
                     enc, Bp, vv, W_e1,b_e1, W_e2,b_e2, out);
}

// Round 2
// 234.709 us; speedup vs baseline: 1.5285x; 1.5285x over previous
//
#include <hip/hip_runtime.h>

#define EE 256
#define SS 2048
#define BB 64
#define RN 50
#define OSTR 8242   // 50 + 4*2048

typedef __attribute__((ext_vector_type(4))) float vf4;
typedef __attribute__((ext_vector_type(8))) short s8v;
typedef __attribute__((ext_vector_type(4))) unsigned short u16x4;

__device__ __forceinline__ unsigned short f2bf(float f){
  unsigned int u = __float_as_uint(f);
  u += 0x7fffu + ((u >> 16) & 1u);   // RNE
  return (unsigned short)(u >> 16);
}
__device__ __forceinline__ float sigm(float x){ return 1.0f/(1.0f + __expf(-x)); }
__device__ __forceinline__ float dot4(vf4 a, vf4 b){ return a.x*b.x + a.y*b.y + a.z*b.z + a.w*b.w; }

// ---------------- 1a) gather + transpose x inputs, h0, c0 --------------------
// grid 256: part = bid>>6 (0..2 = xT for step, 3 = hT/cT), b = bid&63
__global__ __launch_bounds__(256) void k_pre(
  const float* __restrict__ enc, const float* __restrict__ h0, const float* __restrict__ c0,
  const int* __restrict__ r_in, const int* __restrict__ k1, const int* __restrict__ k2,
  const float* __restrict__ sos, const float* __restrict__ rel,
  float* __restrict__ xT, float* __restrict__ hT0, float* __restrict__ cT)
{
  int bid = blockIdx.x, t = threadIdx.x;
  int part = bid >> 6, b = bid & 63;
  if (part == 0){
    xT[(size_t)0*EE*BB + t*BB + b] = sos[t];
  } else if (part == 1){
    xT[(size_t)1*EE*BB + t*BB + b] = rel[r_in[b]*EE + t];
  } else if (part == 2){
    int i1 = k1[b], i2 = k2[b];
    xT[(size_t)2*EE*BB + t*BB + b] =
      enc[((size_t)b*SS + i1)*EE + t] + enc[((size_t)b*SS + i2)*EE + t];
  } else {
    hT0[t*BB + b] = h0[b*EE + t];
    cT [t*BB + b] = c0[b*EE + t];
  }
}

// ---------------- 1b) one LSTM step: gates GEMV + update ---------------------
// grid 256 (e = blockIdx), 4 waves = gate types i,f,g,o; lane = batch
__global__ __launch_bounds__(256) void k_step(
  const float* __restrict__ hT_cur, const float* __restrict__ xT_st,
  const float* __restrict__ W_ih, const float* __restrict__ W_hh,
  const float* __restrict__ b_ih, const float* __restrict__ b_hh,
  float* __restrict__ cT, float* __restrict__ hT_next, float* __restrict__ hs_st)
{
  int e = blockIdx.x, tid = threadIdx.x;
  int w = tid >> 6, b = tid & 63;
  int grow = w*EE + e;
  const float* wh = W_hh + (size_t)grow*EE;
  const float* wi = W_ih + (size_t)grow*EE;
  float acc = b_ih[grow] + b_hh[grow];
  #pragma unroll 4
  for (int k4 = 0; k4 < EE/4; ++k4){
    vf4 wh4 = *(const vf4*)(wh + k4*4);
    vf4 wi4 = *(const vf4*)(wi + k4*4);
    int k = k4*4;
    acc += hT_cur[(k+0)*BB+b]*wh4.x + hT_cur[(k+1)*BB+b]*wh4.y
         + hT_cur[(k+2)*BB+b]*wh4.z + hT_cur[(k+3)*BB+b]*wh4.w;
    acc += xT_st[(k+0)*BB+b]*wi4.x + xT_st[(k+1)*BB+b]*wi4.y
         + xT_st[(k+2)*BB+b]*wi4.z + xT_st[(k+3)*BB+b]*wi4.w;
  }
  __shared__ float sm[4][BB];
  sm[w][b] = acc;
  __syncthreads();
  if (tid < BB){
    float iv = sm[0][tid], fv = sm[1][tid], gv = sm[2][tid], ov = sm[3][tid];
    float cprev = cT[e*BB + tid];
    float cn = sigm(fv)*cprev + sigm(iv)*tanhf(gv);
    float hn = sigm(ov)*tanhf(cn);
    cT[e*BB + tid] = cn;
    hT_next[e*BB + tid] = hn;
    hs_st[(size_t)tid*EE + e] = hn;
  }
}

// ---------------- 2) scores for all 3 queries + per-chunk softmax stats ------
__global__ __launch_bounds__(256) void k_scores(
  const float* __restrict__ enc, const float* __restrict__ hs,
  float* __restrict__ scw, float* __restrict__ stats)
{
  int bid = blockIdx.x; int b = bid >> 3, ch = bid & 7;
  int tid = threadIdx.x, lane = tid & 63, wv = tid >> 6;
  __shared__ float hsm[3][EE];
  __shared__ float red[3][4];
  __shared__ float mg[3];
  for (int i = tid; i < 3*EE; i += 256) hsm[i>>8][i&255] = hs[((size_t)(i>>8)*BB + b)*EE + (i&255)];
  __syncthreads();
  int s = ch*256 + tid;
  const vf4* er = (const vf4*)(enc + ((size_t)b*SS + s)*EE);
  const vf4* q0 = (const vf4*)hsm[0];
  const vf4* q1 = (const vf4*)hsm[1];
  const vf4* q2 = (const vf4*)hsm[2];
  float a0=0.f, a1=0.f, a2=0.f;
  #pragma unroll 8
  for (int k = 0; k < EE/4; ++k){
    vf4 ev = er[k];
    a0 += dot4(ev, q0[k]);
    a1 += dot4(ev, q1[k]);
    a2 += dot4(ev, q2[k]);
  }
  scw[(size_t)(0*BB+b)*SS + s] = a0;
  scw[(size_t)(1*BB+b)*SS + s] = a1;
  scw[(size_t)(2*BB+b)*SS + s] = a2;
  float m0=a0, m1=a1, m2=a2;
  #pragma unroll
  for (int d=1; d<64; d<<=1){
    m0 = fmaxf(m0, __shfl_xor(m0,d));
    m1 = fmaxf(m1, __shfl_xor(m1,d));
    m2 = fmaxf(m2, __shfl_xor(m2,d));
  }
  if (lane==0){ red[0][wv]=m0; red[1][wv]=m1; red[2][wv]=m2; }
  __syncthreads();
  if (tid < 3) mg[tid] = fmaxf(fmaxf(red[tid][0],red[tid][1]), fmaxf(red[tid][2],red[tid][3]));
  __syncthreads();
  float e0 = __expf(a0-mg[0]), e1 = __expf(a1-mg[1]), e2 = __expf(a2-mg[2]);
  #pragma unroll
  for (int d=1; d<64; d<<=1){
    e0 += __shfl_xor(e0,d); e1 += __shfl_xor(e1,d); e2 += __shfl_xor(e2,d);
  }
  if (lane==0){ red[0][wv]=e0; red[1][wv]=e1; red[2][wv]=e2; }
  __syncthreads();
  if (tid < 3){
    float l = red[tid][0]+red[tid][1]+red[tid][2]+red[tid][3];
    int o = ((tid*BB + b)*8 + ch)*2;
    stats[o] = mg[tid]; stats[o+1] = l;
  }
}

// ---------------- 3) mix (weighted sum) -- writes over scw region (aliased) --
__global__ __launch_bounds__(256) void k_mix(
  const float* __restrict__ enc, const float* __restrict__ scm,
  const float* __restrict__ stats, float* __restrict__ mixc)
{
  int bid = blockIdx.x; int b = bid >> 3, ch = bid & 7;
  int tid = threadIdx.x, lane = tid & 63, wv = tid >> 6;
  __shared__ float wgt[3][256];
  __shared__ vf4 mpart[4][3][64];
  float mm[3], inv[3];
  #pragma unroll
  for (int t=0;t<3;t++){
    float m = -1e30f;
    for (int c=0;c<8;c++) m = fmaxf(m, stats[((t*BB+b)*8 + c)*2]);
    float l = 0.f;
    for (int c=0;c<8;c++){ int o=((t*BB+b)*8+c)*2; l += stats[o+1]*__expf(stats[o]-m); }
    mm[t]=m; inv[t]=1.0f/l;
  }
  int s = ch*256 + tid;
  wgt[0][tid] = __expf(scm[(size_t)(0*BB+b)*SS + s] - mm[0]) * inv[0];
  wgt[1][tid] = __expf(scm[(size_t)(1*BB+b)*SS + s] - mm[1]) * inv[1];
  wgt[2][tid] = __expf(scm[(size_t)(2*BB+b)*SS + s] - mm[2]) * inv[2];
  __syncthreads();
  vf4 a0 = (vf4)0.0f, a1 = (vf4)0.0f, a2 = (vf4)0.0f;
  for (int i=0;i<64;++i){
    int sl = wv*64 + i;
    vf4 ev = *(const vf4*)(enc + ((size_t)b*SS + ch*256 + sl)*EE + lane*4);
    a0 += ev*wgt[0][sl]; a1 += ev*wgt[1][sl]; a2 += ev*wgt[2][sl];
  }
  mpart[wv][0][lane]=a0; mpart[wv][1][lane]=a1; mpart[wv][2][lane]=a2;
  __syncthreads();
  if (tid < 192){
    int t = tid >> 6, e4 = tid & 63;
    vf4 sum = mpart[0][t][e4] + mpart[1][t][e4] + mpart[2][t][e4] + mpart[3][t][e4];
    *(vf4*)(mixc + ((size_t)(t*BB+b)*8 + e4*0 + ch)*EE + e4*4) = sum;
  }
}

// ---------------- 4) out_t = tanh([mix,h]W_attn^T+b); t1 logits; V vectors ---
__global__ __launch_bounds__(256) void k_post(
  const float* __restrict__ mixc, const float* __restrict__ hs,
  const float* __restrict__ W_attn, const float* __restrict__ b_attn,
  const float* __restrict__ W_rel, const float* __restrict__ b_rel,
  const float* __restrict__ W_conv, const float* __restrict__ b_conv,
  float* __restrict__ out, float* __restrict__ vv)
{
  int b = blockIdx.x, t = threadIdx.x;
  __shared__ float comb[3][2*EE];
  __shared__ float o1[EE], o2[EE], o3[EE];
  #pragma unroll
  for (int q=0;q<3;q++){
    float m = 0.f;
    for (int c=0;c<8;c++) m += mixc[((size_t)(q*BB+b)*8 + c)*EE + t];
    comb[q][t] = m;
    comb[q][EE+t] = hs[((size_t)q*BB + b)*EE + t];
  }
  __syncthreads();
  float a0 = b_attn[t], a1 = a0, a2 = a0;
  const vf4* wr = (const vf4*)(W_attn + (size_t)t*2*EE);
  const vf4* c0v = (const vf4*)comb[0];
  const vf4* c1v = (const vf4*)comb[1];
  const vf4* c2v = (const vf4*)comb[2];
  #pragma unroll 4
  for (int k=0;k<2*EE/4;++k){
    vf4 w = wr[k];
    a0 += dot4(w, c0v[k]); a1 += dot4(w, c1v[k]); a2 += dot4(w, c2v[k]);
  }
  o1[t]=tanhf(a0); o2[t]=tanhf(a1); o3[t]=tanhf(a2);
  __syncthreads();
  if (t < RN){
    float acc = b_rel[t];
    const vf4* wrel = (const vf4*)(W_rel + (size_t)t*EE);
    const vf4* ov = (const vf4*)o1;
    for (int k=0;k<EE/4;++k) acc += dot4(wrel[k], ov[k]);
    out[(size_t)b*OSTR + t] = acc;
  }
  // vec-part of conv: V_k[o] = sum_i out[i]*W_conv[o, 256+i, k]
  float va0=0,va1=0,va2=0, vb0=0,vb1=0,vb2=0;
  const float* wc = W_conv + (size_t)t*2*EE*3 + EE*3;
  for (int i=0;i<EE;++i){
    float w0 = wc[i*3+0], w1 = wc[i*3+1], w2 = wc[i*3+2];
    float x2 = o2[i], x3 = o3[i];
    va0 += x2*w0; va1 += x2*w1; va2 += x2*w2;
    vb0 += x3*w0; vb1 += x3*w1; vb2 += x3*w2;
  }
  float bc = b_conv[t];
  vv[((0*3+0)*BB + b)*EE + t] = va0+va1+va2+bc;  // interior
  vv[((0*3+1)*BB + b)*EE + t] = va1+va2+bc;      // s==0 (tap0 clipped)
  vv[((0*3+2)*BB + b)*EE + t] = va0+va1+bc;      // s==S-1 (tap2 clipped)
  vv[((1*3+0)*BB + b)*EE + t] = vb0+vb1+vb2+bc;
  vv[((1*3+1)*BB + b)*EE + t] = vb1+vb2+bc;
  vv[((1*3+2)*BB + b)*EE + t] = vb0+vb1+bc;
}

// ---------------- 5) pack B (= W_conv enc-channels) into MFMA-frag order -----
__global__ __launch_bounds__(256) void k_bprep(const float* __restrict__ W_conv,
                                               unsigned short* __restrict__ Bp)
{
  int gid = blockIdx.x*256 + threadIdx.x;   // < 24576
  int kc  = gid >> 10;
  int rem = gid & 1023;
  int ni  = rem >> 6;
  int l   = rem & 63;
  int o   = ni*16 + (l & 15);
  int kbase = kc*32 + ((l >> 4) << 3);
  u16x4 lo4, hi4;
  #pragma unroll
  for (int j=0;j<8;++j){
    int k = kbase + j; int ktap = k >> 8; int i = k & 255;
    unsigned short v = f2bf(W_conv[((size_t)o*512 + i)*3 + ktap]);
    if (j<4){ if(j==0)lo4.x=v; else if(j==1)lo4.y=v; else if(j==2)lo4.z=v; else lo4.w=v; }
    else    { if(j==4)hi4.x=v; else if(j==5)hi4.y=v; else if(j==6)hi4.z=v; else hi4.w=v; }
  }
  u16x4* dst = (u16x4*)(Bp + (size_t)gid*8);
  dst[0] = lo4; dst[1] = hi4;
}

// ---------------- 6) conv GEMM (M=BS,N=256,K=768) + fused relu-dot epilogue --
__global__ __launch_bounds__(256) void k_conv(
  const float* __restrict__ enc, const unsigned short* __restrict__ Bp,
  const float* __restrict__ vv,
  const float* __restrict__ W_e1, const float* __restrict__ b_e1,
  const float* __restrict__ W_e2, const float* __restrict__ b_e2,
  float* __restrict__ out)
{
  int stile = blockIdx.x, b = blockIdx.y;
  int s0 = stile*64;
  int tid = threadIdx.x, lane = tid & 63, w = tid >> 6;
  int lo = lane & 15, hi = lane >> 4;
  __shared__ __align__(16) unsigned short Ab[66*256];  // rows s0-1 .. s0+64, bf16, swizzled
  __shared__ float part[4][64][4];

  {  // stage A (fp32 -> bf16) with XOR swizzle
    const float* eb = enc + (size_t)b*SS*EE;
    for (int idx = tid; idx < 66*64; idx += 256){
      int r = idx >> 6, c4 = idx & 63;
      int s = s0 - 1 + r;
      vf4 v = (vf4)0.0f;
      if (s >= 0 && s < SS) v = *(const vf4*)(eb + (size_t)s*EE + c4*4);
      u16x4 pk; pk.x=f2bf(v.x); pk.y=f2bf(v.y); pk.z=f2bf(v.z); pk.w=f2bf(v.w);
      int byte = (r*512 + c4*8) ^ ((r & 7) << 4);
      *(u16x4*)((char*)Ab + byte) = pk;
    }
  }
  __syncthreads();

  vf4 acc[4][4];
  #pragma unroll
  for (int mi=0;mi<4;++mi){
    #pragma unroll
    for (int ni=0;ni<4;++ni) acc[mi][ni] = (vf4)0.0f;
  }
  const s8v* Bp8 = (const s8v*)Bp;
  s8v bf[4], bfn[4];
  #pragma unroll
  for (int ni=0;ni<4;++ni) bf[ni] = Bp8[((0*16 + (w*4+ni)) << 6) + lane];

  for (int kc=0; kc<24; ++kc){
    int ktap = kc >> 3;
    int colb = ((kc & 7) << 6) + (hi << 4);
    s8v af[4];
    #pragma unroll
    for (int mi=0;mi<4;++mi){
      int row = mi*16 + lo + ktap;
      int byte = row*512 + (colb ^ ((row & 7) << 4));
      af[mi] = *(const s8v*)((const char*)Ab + byte);
    }
    if (kc < 23){
      #pragma unroll
      for (int ni=0;ni<4;++ni) bfn[ni] = Bp8[(((kc+1)*16 + (w*4+ni)) << 6) + lane];
    }
    #pragma unroll
    for (int mi=0;mi<4;++mi){
      #pragma unroll
      for (int ni=0;ni<4;++ni)
        acc[mi][ni] = __builtin_amdgcn_mfma_f32_16x16x32_bf16(af[mi], bf[ni], acc[mi][ni], 0, 0, 0);
    }
    #pragma unroll
    for (int ni=0;ni<4;++ni) bf[ni] = bfn[ni];
  }

  // fused epilogue: e = relu(conv_enc + V + b_conv) . w{1,2} for both streams
  float vaI[4],vaL[4],vaR[4],vbI[4],vbL[4],vbR[4],w1v[4],w2v[4];
  #pragma unroll
  for (int ni=0;ni<4;++ni){
    int o = w*64 + ni*16 + lo;
    vaI[ni] = vv[((0*3+0)*BB + b)*EE + o];
    vaL[ni] = vv[((0*3+1)*BB + b)*EE + o];
    vaR[ni] = vv[((0*3+2)*BB + b)*EE + o];
    vbI[ni] = vv[((1*3+0)*BB + b)*EE + o];
    vbL[ni] = vv[((1*3+1)*BB + b)*EE + o];
    vbR[ni] = vv[((1*3+2)*BB + b)*EE + o];
    w1v[ni] = W_e1[o]; w2v[ni] = W_e2[o];
  }
  float be1 = b_e1[0], be2 = b_e2[0];
  #pragma unroll
  for (int mi=0;mi<4;++mi){
    #pragma unroll
    for (int j=0;j<4;++j){
      int m = mi*16 + hi*4 + j;
      int s = s0 + m;
      float p0=0,p1=0,p2=0,p3=0;
      #pragma unroll
      for (int ni=0;ni<4;++ni){
        float cvv = acc[mi][ni][j];
        float va = vaI[ni], vb = vbI[ni];
        if (s == 0){ va = vaL[ni]; vb = vbL[ni]; }
        else if (s == SS-1){ va = vaR[ni]; vb = vbR[ni]; }
        float ca = fmaxf(cvv + va, 0.0f);
        float cb = fmaxf(cvv + vb, 0.0f);
        p0 += ca*w1v[ni]; p1 += ca*w2v[ni];
        p2 += cb*w1v[ni]; p3 += cb*w2v[ni];
      }
      #pragma unroll
      for (int d=1; d<16; d<<=1){
        p0 += __shfl_xor(p0,d); p1 += __shfl_xor(p1,d);
        p2 += __shfl_xor(p2,d); p3 += __shfl_xor(p3,d);
      }
      if (lo == 0){ part[w][m][0]=p0; part[w][m][1]=p1; part[w][m][2]=p2; part[w][m][3]=p3; }
    }
  }
  __syncthreads();
  {
    int m = tid >> 2, oi = tid & 3;
    float r = part[0][m][oi] + part[1][m][oi] + part[2][m][oi] + part[3][m][oi];
    r += (oi & 1) ? be2 : be1;
    out[(size_t)b*OSTR + RN + oi*SS + (s0 + m)] = r;
  }
}

extern "C" void kernel_launch(void* const* d_in, const int* in_sizes, int n_in,
                              void* d_out, int out_size, void* d_ws, size_t ws_size,
                              hipStream_t stream)
{
  const float* enc   = (const float*)d_in[0];
  const float* h0    = (const float*)d_in[1];
  const float* c0    = (const float*)d_in[2];
  const int*   r_in  = (const int*)d_in[3];
  const int*   k1    = (const int*)d_in[4];
  const int*   k2    = (const int*)d_in[5];
  const float* W_ih  = (const float*)d_in[6];
  const float* W_hh  = (const float*)d_in[7];
  const float* b_ih  = (const float*)d_in[8];
  const float* b_hh  = (const float*)d_in[9];
  const float* W_attn= (const float*)d_in[10];
  const float* b_attn= (const float*)d_in[11];
  const float* W_conv= (const float*)d_in[12];
  const float* b_conv= (const float*)d_in[13];
  const float* sos   = (const float*)d_in[14];
  const float* rel   = (const float*)d_in[15];
  const float* W_rel = (const float*)d_in[16];
  const float* b_rel = (const float*)d_in[17];
  const float* W_e1  = (const float*)d_in[18];
  const float* b_e1  = (const float*)d_in[19];
  const float* W_e2  = (const float*)d_in[20];
  const float* b_e2  = (const float*)d_in[21];
  float* out = (float*)d_out;
  char* ws = (char*)d_ws;

  float* hs    = (float*)(ws);                 // 3*64*256 f32        (196608 B)
  float* vv    = (float*)(ws + 196608);        // 2*3*64*256 f32      (393216 B)
  float* stats = (float*)(ws + 589824);        // 3*64*8*2 f32        ( 12288 B)
  float* scw   = (float*)(ws + 602112);        // 3*64*2048 f32       (1572864 B) [reused as mixc]
  unsigned short* Bp = (unsigned short*)(ws + 2174976); // 24*16*64*8 bf16 (393216 B)
  float* xT    = (float*)(ws + 2568192);       // 3*256*64 f32        (196608 B)
  float* hTa   = (float*)(ws + 2764800);       // 256*64 f32          ( 65536 B)
  float* hTb   = (float*)(ws + 2830336);       // 256*64 f32          ( 65536 B)
  float* cT    = (float*)(ws + 2895872);       // 256*64 f32          ( 65536 B)

  hipLaunchKernelGGL(k_pre,   dim3(256), dim3(256), 0, stream,
                     enc,h0,c0,r_in,k1,k2,sos,rel, xT,hTa,cT);
  hipLaunchKernelGGL(k_step,  dim3(256), dim3(256), 0, stream,
                     hTa, xT + 0*EE*BB, W_ih,W_hh,b_ih,b_hh, cT, hTb, hs + 0*BB*EE);
  hipLaunchKernelGGL(k_step,  dim3(256), dim3(256), 0, stream,
                     hTb, xT + 1*EE*BB, W_ih,W_hh,b_ih,b_hh, cT, hTa, hs + 1*BB*EE);
  hipLaunchKernelGGL(k_step,  dim3(256), dim3(256), 0, stream,
                     hTa, xT + 2*EE*BB, W_ih,W_hh,b_ih,b_hh, cT, hTb, hs + 2*BB*EE);
  hipLaunchKernelGGL(k_scores,dim3(512), dim3(256), 0, stream, enc, hs, scw, stats);
  hipLaunchKernelGGL(k_mix,   dim3(512), dim3(256), 0, stream, enc, scw, stats, scw);
  hipLaunchKernelGGL(k_post,  dim3(64),  dim3(256), 0, stream,
                     scw, hs, W_attn,b_attn, W_rel,b_rel, W_conv,b_conv, out, vv);
  hipLaunchKernelGGL(k_bprep, dim3(96),  dim3(256), 0, stream, W_conv, Bp);
  hipLaunchKernelGGL(k_conv,  dim3(32,64), dim3(256), 0, stream,
                     enc, Bp, vv, W_e1,b_e1, W_e2,b_e2, out);
}